// Round 10
// baseline (108.156 us; speedup 1.0000x reference)
//
#include <hip/hip_runtime.h>
#include <stdint.h>

#define NB 4
#define NC 256
// Chunked f2 layout per batch: [level][chunk 0..31][cell][8 bf16 = 16B].
// chunk q = st*4+g holds channels q*8 .. q*8+7 (matches A-fragment need).
#define FB   1392640         // shorts per batch = 256*5440
#define LVO1 1048576         // level bases (shorts): L0=0
#define LVO2 1310720
#define LVO3 1376256

typedef short bf16x8 __attribute__((ext_vector_type(8)));
typedef float f32x4  __attribute__((ext_vector_type(4)));

__device__ __forceinline__ unsigned short f2b(float x){
  uint32_t u = __float_as_uint(x);
  return (unsigned short)((u + 0x7FFFu + ((u >> 16) & 1u)) >> 16);  // RNE
}
__device__ __forceinline__ unsigned int pack2(float a, float b){
  return (unsigned int)f2b(a) | ((unsigned int)f2b(b) << 16);
}

// f2-only preprocessing (unchanged from R9):
// 512 blocks: 8x16-cell region x 64ch -> chunked bf16 for levels 0..3
__global__ __launch_bounds__(256) void prep_all(const float* __restrict__ f2,
                 unsigned short* __restrict__ f2c){
  __shared__ float lds[128*65];                   // 33.3 KB
  __shared__ float l1s[32*65];                    // level-1 sums (fp32)
  __shared__ float l2s[8*65];                     // level-2 sums (fp32)
  const int t = threadIdx.x;
  const int fid = blockIdx.x;                     // 0..511
  const int b = fid >> 7, rest = fid & 127;
  const int reg = rest >> 2, cc = rest & 3;
  const int i0 = (reg >> 2) * 8, j0 = (reg & 3) * 16;
  const int c0 = cc * 64, qb = cc * 8;            // chunks qb..qb+7

  #pragma unroll
  for (int it = 0; it < 8; ++it){
    int q = t + 256*it;                           // 0..2047
    int ch = q >> 5, rc = q & 31, ri = rc >> 2, c4 = rc & 3;
    const float4 v = *(const float4*)(f2 + ((size_t)(b*NC) + c0 + ch)*4096
                                        + (i0+ri)*64 + j0 + c4*4);
    float* dstL = lds + (ri*16 + c4*4)*65 + ch;   // cell stride 65 (pad)
    dstL[0] = v.x; dstL[65] = v.y; dstL[130] = v.z; dstL[195] = v.w;
  }
  __syncthreads();
  unsigned short* f2cB = f2c + (size_t)b*FB;

  // Level 0: 8 chunks x 128 cells, 16B stores
  #pragma unroll
  for (int it = 0; it < 4; ++it){
    int idx = t + 256*it;                         // 0..1023
    int cell = idx & 127, qi = idx >> 7;
    int ci = cell >> 4, cj = cell & 15;
    const float* src = lds + cell*65 + qi*8;
    uint4 v;
    v.x = pack2(src[0], src[1]); v.y = pack2(src[2], src[3]);
    v.z = pack2(src[4], src[5]); v.w = pack2(src[6], src[7]);
    int cellg = (i0+ci)*64 + j0+cj;
    *(uint4*)(f2cB + ((size_t)(qb+qi)*4096 + cellg)*8) = v;
  }
  // Level 1: 32 cells x 8 chunks; stash fp32 sums for level 2
  {
    int cell = t & 31, qi = t >> 5;
    int a = cell >> 3, bc = cell & 7;
    const float* p00 = lds + ((2*a)*16 + 2*bc)*65 + qi*8;
    float s[8];
    #pragma unroll
    for (int j = 0; j < 8; ++j){
      s[j] = p00[j] + p00[65+j] + p00[16*65+j] + p00[17*65+j];
      l1s[cell*65 + qi*8 + j] = s[j];
    }
    uint4 v;
    v.x = pack2(s[0]*0.25f, s[1]*0.25f); v.y = pack2(s[2]*0.25f, s[3]*0.25f);
    v.z = pack2(s[4]*0.25f, s[5]*0.25f); v.w = pack2(s[6]*0.25f, s[7]*0.25f);
    int cellg = ((i0>>1)+a)*32 + (j0>>1)+bc;
    *(uint4*)(f2cB + LVO1 + ((size_t)(qb+qi)*1024 + cellg)*8) = v;
  }
  __syncthreads();
  // Level 2: 8 cells x 8 chunks from l1 sums; stash for level 3
  if (t < 64){
    int cell = t & 7, qi = t >> 3;
    int a2 = cell >> 2, bc2 = cell & 3;
    float s[8];
    #pragma unroll
    for (int j = 0; j < 8; ++j){
      int ch = qi*8 + j;
      s[j] = l1s[((2*a2)*8   + 2*bc2  )*65 + ch] + l1s[((2*a2)*8   + 2*bc2+1)*65 + ch]
           + l1s[((2*a2+1)*8 + 2*bc2  )*65 + ch] + l1s[((2*a2+1)*8 + 2*bc2+1)*65 + ch];
      l2s[cell*65 + ch] = s[j];
    }
    uint4 v;
    v.x = pack2(s[0]*0.0625f, s[1]*0.0625f); v.y = pack2(s[2]*0.0625f, s[3]*0.0625f);
    v.z = pack2(s[4]*0.0625f, s[5]*0.0625f); v.w = pack2(s[6]*0.0625f, s[7]*0.0625f);
    int cellg = ((i0>>2)+a2)*16 + (j0>>2)+bc2;
    *(uint4*)(f2cB + LVO2 + ((size_t)(qb+qi)*256 + cellg)*8) = v;
  }
  __syncthreads();
  // Level 3: 2 cells x 8 chunks from l2 sums
  if (t < 16){
    int cl = t & 1, qi = t >> 1;
    float s[8];
    #pragma unroll
    for (int j = 0; j < 8; ++j){
      int ch = qi*8 + j;
      s[j] = l2s[(0*4 + 2*cl)*65 + ch] + l2s[(0*4 + 2*cl+1)*65 + ch]
           + l2s[(1*4 + 2*cl)*65 + ch] + l2s[(1*4 + 2*cl+1)*65 + ch];
    }
    const float m = 1.0f/64.0f;
    uint4 v;
    v.x = pack2(s[0]*m, s[1]*m); v.y = pack2(s[2]*m, s[3]*m);
    v.z = pack2(s[4]*m, s[5]*m); v.w = pack2(s[6]*m, s[7]*m);
    int cellg = (i0>>3)*8 + (j0>>3) + cl;
    *(uint4*)(f2cB + LVO3 + ((size_t)(qb+qi)*64 + cellg)*8) = v;
  }
}

// Next-pass parameter computation, flat scalars (no struct/lambda: R7's PM
// aggregate forced an alloca -> 57MB scratch spill). Safe for p >= P: k
// clamps to 3 and idxA clamps to cells-1 -> valid address, values unused.
#define MKPASS(pp, oK, oBase, oCells, oW, oYlo, oXlo, oYb, oXb, oRW, oColp, oStride) \
  do { \
    oK = (pp >= pre1) + (pp >= pre2) + (pp >= pre3); \
    const int lp_ = pp - ((oK==0) ? 0 : (oK==1) ? pre1 : (oK==2) ? pre2 : pre3); \
    const int mb_ = oK*8; \
    oYlo = ls_meta[mb_]; oXlo = ls_meta[mb_+1]; oW = ls_meta[mb_+2]; \
    oCells = ls_meta[mb_+3]; oRW = __int_as_float(ls_meta[mb_+4]); \
    const int lvoc_ = ls_meta[mb_+5]; \
    const int h_ = 64 >> oK, ncl_ = h_*h_; \
    oBase = lp_ << 4; \
    const int idxA_ = min(oBase + n, oCells - 1); \
    const int by_ = (int)fmaf((float)idxA_, oRW, 0.004f); \
    const int bx_ = idxA_ - by_*oW; \
    oColp = f2cB + lvoc_ + ((size_t)(g*ncl_ + (oYlo + by_)*h_ + (oXlo + bx_)) << 3); \
    oStride = ncl_ << 5; \
    oYb = (oK==0) ? y0n0 : (oK==1) ? y0n1 : (oK==2) ? y0n2 : y0n3; \
    oXb = (oK==0) ? x0n0 : (oK==1) ? x0n1 : (oK==2) ? x0n2 : x0n3; \
  } while(0)

// Block = 4x4 pixel tile, all 4 levels. Chunked A-layout. Pass loop prefetches
// the wave's NEXT pass in-place: each af reg is reloaded right after its MFMA
// consumes it (WAR reuse -> peak fragment liveness stays 32+32 regs).
__global__ __launch_bounds__(256, 4) void lookup_main(const float* __restrict__ flow,
                 const float* __restrict__ f1,
                 const unsigned short* __restrict__ f2c,
                 float* __restrict__ out){
  const int lane = threadIdx.x & 63;
  const int wid  = threadIdx.x >> 6;
  const int blk = blockIdx.x;
  const int xs = blk & 7;                         // XCD swizzle: batch per XCD-pair
  const int bb = xs >> 1;
  const int tile = ((blk >> 3) << 1) | (xs & 1);  // 0..255
  const int ti4 = (tile >> 4) << 2;
  const int tj4 = (tile & 15) << 2;

  __shared__ float box[4*16*113];                 // [level][pixel][10x10, pad 113]
  __shared__ unsigned short f1s[16*264];          // [pixel][ch], pad stride 264
  __shared__ int   ls_y0[64], ls_x0[64];          // [level][pixel]
  __shared__ float ls_f[32];                      // fy[16], fx[16]
  __shared__ int   ls_meta[32];                   // [level][8]

  {
    float4* b4 = (float4*)box;
    for (int q = threadIdx.x; q < (4*16*113)/4; q += 256)
      b4[q] = make_float4(0.f, 0.f, 0.f, 0.f);
  }

  // Stage f1 columns for the tile's 16 pixels: thread t = channel t.
  {
    const float* f1b = f1 + ((size_t)(bb*NC) + threadIdx.x)*4096;
    #pragma unroll
    for (int r = 0; r < 4; ++r){
      const float4 v = *(const float4*)(f1b + (ti4 + r)*64 + tj4);
      const int px = r*4;
      f1s[(px+0)*264 + threadIdx.x] = f2b(v.x);
      f1s[(px+1)*264 + threadIdx.x] = f2b(v.y);
      f1s[(px+2)*264 + threadIdx.x] = f2b(v.z);
      f1s[(px+3)*264 + threadIdx.x] = f2b(v.w);
    }
  }

  const int n = lane & 15;                        // MFMA n = pixel column
  const int g = lane >> 4;                        // MFMA k-chunk group
  const int pn = ((ti4 + (n >> 2)) << 6) + tj4 + (n & 3);

  if (wid == 0){                                  // lane = k*16 + n
    const int k = g;
    const int i_n = pn >> 6, j_n = pn & 63;
    const float fy = flow[((bb*2 + 0)*64 + i_n)*64 + j_n];
    const float fx = flow[((bb*2 + 1)*64 + i_n)*64 + j_n];
    if (k == 0){ ls_f[n] = fy; ls_f[16 + n] = fx; }
    const int h = 64 >> k;
    const float inv = 1.0f / (float)(1 << k);
    const float s = (float)(h - 1) / (float)h;
    const float yc = ((float)i_n + fy) * inv;
    const float xc = ((float)j_n + fx) * inv;
    const int y0 = (int)floorf((yc - 4.0f) * s);
    const int x0 = (int)floorf((xc - 4.0f) * s);
    ls_y0[k*16 + n] = y0;
    ls_x0[k*16 + n] = x0;
    int ymin = y0, ymax = y0, xmin = x0, xmax = x0;
    #pragma unroll
    for (int m = 1; m < 16; m <<= 1){
      ymin = min(ymin, __shfl_xor(ymin, m));
      ymax = max(ymax, __shfl_xor(ymax, m));
      xmin = min(xmin, __shfl_xor(xmin, m));
      xmax = max(xmax, __shfl_xor(xmax, m));
    }
    if (n == 0){
      int ylo = max(ymin, 0), yhi = min(ymax + 9, h - 1);
      int xlo = max(xmin, 0), xhi = min(xmax + 9, h - 1);
      int H = max(yhi - ylo + 1, 0), W = max(xhi - xlo + 1, 0);
      int cells = W * H;
      ls_meta[k*8 + 0] = ylo;
      ls_meta[k*8 + 1] = xlo;
      ls_meta[k*8 + 2] = W;
      ls_meta[k*8 + 3] = cells;
      ls_meta[k*8 + 4] = __float_as_int(1.0f / (float)W);
      ls_meta[k*8 + 5] = (k==0) ? 0 : (k==1) ? LVO1 : (k==2) ? LVO2 : LVO3;
      ls_meta[k*8 + 6] = (cells + 15) >> 4;       // passes
    }
  }
  __syncthreads();

  // B fragments: f1 columns of the tile's 16 pixels, from LDS (registers)
  bf16x8 bfr[8];
  #pragma unroll
  for (int st = 0; st < 8; ++st)
    bfr[st] = *(const bf16x8*)(&f1s[n*264 + st*32 + g*8]);

  const int y0n0 = ls_y0[n],      x0n0 = ls_x0[n];
  const int y0n1 = ls_y0[16 + n], x0n1 = ls_x0[16 + n];
  const int y0n2 = ls_y0[32 + n], x0n2 = ls_x0[32 + n];
  const int y0n3 = ls_y0[48 + n], x0n3 = ls_x0[48 + n];
  const int pre1 = ls_meta[6];
  const int pre2 = pre1 + ls_meta[14];
  const int pre3 = pre2 + ls_meta[22];
  const int P    = pre3 + ls_meta[30];
  const unsigned short* f2cB = f2c + (size_t)bb*FB;

  {
    int p = wid;                                  // P >= 25 always, so p < P
    int cK, cBase, cCells, cW, cYlo, cXlo, cYb, cXb, cStride;
    float cRW;
    const unsigned short* cColp;
    MKPASS(p, cK, cBase, cCells, cW, cYlo, cXlo, cYb, cXb, cRW, cColp, cStride);
    bf16x8 af0 = *(const bf16x8*)(cColp);
    bf16x8 af1 = *(const bf16x8*)(cColp + (size_t)cStride);
    bf16x8 af2 = *(const bf16x8*)(cColp + (size_t)2*cStride);
    bf16x8 af3 = *(const bf16x8*)(cColp + (size_t)3*cStride);
    bf16x8 af4 = *(const bf16x8*)(cColp + (size_t)4*cStride);
    bf16x8 af5 = *(const bf16x8*)(cColp + (size_t)5*cStride);
    bf16x8 af6 = *(const bf16x8*)(cColp + (size_t)6*cStride);
    bf16x8 af7 = *(const bf16x8*)(cColp + (size_t)7*cStride);
    do {
      const int np = p + 4;
      int nK, nBase, nCells, nW, nYlo, nXlo, nYb, nXb, nStride;
      float nRW;
      const unsigned short* nColp;
      MKPASS(np, nK, nBase, nCells, nW, nYlo, nXlo, nYb, nXb, nRW, nColp, nStride);

      f32x4 acc0 = {0.f,0.f,0.f,0.f}, acc1 = {0.f,0.f,0.f,0.f};
      acc0 = __builtin_amdgcn_mfma_f32_16x16x32_bf16(af0, bfr[0], acc0, 0, 0, 0);
      acc1 = __builtin_amdgcn_mfma_f32_16x16x32_bf16(af1, bfr[1], acc1, 0, 0, 0);
      af0 = *(const bf16x8*)(nColp);
      af1 = *(const bf16x8*)(nColp + (size_t)nStride);
      acc0 = __builtin_amdgcn_mfma_f32_16x16x32_bf16(af2, bfr[2], acc0, 0, 0, 0);
      acc1 = __builtin_amdgcn_mfma_f32_16x16x32_bf16(af3, bfr[3], acc1, 0, 0, 0);
      af2 = *(const bf16x8*)(nColp + (size_t)2*nStride);
      af3 = *(const bf16x8*)(nColp + (size_t)3*nStride);
      acc0 = __builtin_amdgcn_mfma_f32_16x16x32_bf16(af4, bfr[4], acc0, 0, 0, 0);
      acc1 = __builtin_amdgcn_mfma_f32_16x16x32_bf16(af5, bfr[5], acc1, 0, 0, 0);
      af4 = *(const bf16x8*)(nColp + (size_t)4*nStride);
      af5 = *(const bf16x8*)(nColp + (size_t)5*nStride);
      acc0 = __builtin_amdgcn_mfma_f32_16x16x32_bf16(af6, bfr[6], acc0, 0, 0, 0);
      acc1 = __builtin_amdgcn_mfma_f32_16x16x32_bf16(af7, bfr[7], acc1, 0, 0, 0);
      af6 = *(const bf16x8*)(nColp + (size_t)6*nStride);
      af7 = *(const bf16x8*)(nColp + (size_t)7*nStride);

      // C/D: col = lane&15 = pixel n, row = cell = g*4 + r  [m89-verified]
      #pragma unroll
      for (int r = 0; r < 4; ++r){
        const int ci = cBase + (g << 2) + r;
        if (ci < cCells){
          const int byc = (int)fmaf((float)ci, cRW, 0.004f);
          const int bxc = ci - byc*cW;
          const int ry = cYlo + byc - cYb;
          const int rx = cXlo + bxc - cXb;
          if ((unsigned)ry < 10u && (unsigned)rx < 10u)
            box[(cK*16 + n)*113 + ry*10 + rx] = (acc0[r] + acc1[r]) * 0.0625f;
        }
      }
      cK = nK; cBase = nBase; cCells = nCells; cW = nW; cRW = nRW;
      cYlo = nYlo; cXlo = nXlo; cYb = nYb; cXb = nXb;
      p = np;
    } while (p < P);
  }
  __syncthreads();

  // Tap phase: wave w = level w; 16 pixels sequential, 41 taps in lanes.
  int dy = 0, dx = 0;
  {
    int rem = lane;
    #pragma unroll
    for (int ry = -4; ry <= 4; ++ry){
      int ab = ry < 0 ? -ry : ry;
      int ln = 9 - 2*ab;
      if (rem >= 0 && rem < ln){ dy = ry; dx = rem + (ab - 4); }
      rem -= ln;
    }
  }
  const int k = wid;
  const float inv = 1.0f / (float)(1 << k);
  const float s = (float)((64 >> k) - 1) / (float)(64 >> k);
  if (lane < 41){
    for (int t = 0; t < 16; ++t){
      const int pt = ((ti4 + (t >> 2)) << 6) + tj4 + (t & 3);
      const float fy = ls_f[t], fx = ls_f[16 + t];
      const float yc = ((float)(pt >> 6) + fy) * inv;
      const float xc = ((float)(pt & 63) + fx) * inv;
      const float py = (yc + (float)dy) * s;
      const float px = (xc + (float)dx) * s;
      const float fy0 = floorf(py), fx0 = floorf(px);
      const float wy1 = py - fy0, wx1 = px - fx0;
      const float wy0 = 1.0f - wy1, wx0 = 1.0f - wx1;
      const int iy = (int)fy0 - ls_y0[k*16 + t];
      const int ix = (int)fx0 - ls_x0[k*16 + t];
      const float* bx_ = &box[(k*16 + t)*113 + iy*10 + ix];
      const float v = wy0*(wx0*bx_[0] + wx1*bx_[1]) + wy1*(wx0*bx_[10] + wx1*bx_[11]);
      out[((size_t)(bb*4096 + pt)*4 + k)*41 + lane] = v;
    }
  }
}

extern "C" void kernel_launch(void* const* d_in, const int* in_sizes, int n_in,
                              void* d_out, int out_size, void* d_ws, size_t ws_size,
                              hipStream_t stream){
  const float* feat1 = (const float*)d_in[0];
  const float* feat2 = (const float*)d_in[1];
  const float* flow  = (const float*)d_in[2];
  float* out = (float*)d_out;
  unsigned short* f2c = (unsigned short*)d_ws;                 // 4*FB bf16 (chunked)

  prep_all<<<512, 256, 0, stream>>>(feat2, f2c);
  lookup_main<<<1024, 256, 0, stream>>>(flow, feat1, f2c, out);
}

// Round 12
// 107.353 us; speedup vs baseline: 1.0075x; 1.0075x over previous
//
#include <hip/hip_runtime.h>
#include <stdint.h>

#define NB 4
#define NC 256
// Chunked f2 layout per batch: [level][chunk 0..31][cell][8 bf16 = 16B].
// chunk q = st*4+g holds channels q*8 .. q*8+7 (matches A-fragment need).
#define FB   1392640         // shorts per batch = 256*5440
#define LVO1 1048576         // level bases (shorts): L0=0
#define LVO2 1310720
#define LVO3 1376256

typedef short bf16x8 __attribute__((ext_vector_type(8)));
typedef float f32x4  __attribute__((ext_vector_type(4)));

__device__ __forceinline__ unsigned short f2b(float x){
  uint32_t u = __float_as_uint(x);
  return (unsigned short)((u + 0x7FFFu + ((u >> 16) & 1u)) >> 16);  // RNE
}
__device__ __forceinline__ unsigned int pack2(float a, float b){
  return (unsigned int)f2b(a) | ((unsigned int)f2b(b) << 16);
}

// f2-only preprocessing:
// 512 blocks: 8x16-cell region x 64ch -> chunked bf16 for levels 0..3
// (levels 1..3 pooled from fp32 LDS, single bf16 round)
__global__ __launch_bounds__(256) void prep_all(const float* __restrict__ f2,
                 unsigned short* __restrict__ f2c){
  __shared__ float lds[128*65];                   // 33.3 KB
  __shared__ float l1s[32*65];                    // level-1 sums (fp32)
  __shared__ float l2s[8*65];                     // level-2 sums (fp32)
  const int t = threadIdx.x;
  const int fid = blockIdx.x;                     // 0..511
  const int b = fid >> 7, rest = fid & 127;
  const int reg = rest >> 2, cc = rest & 3;
  const int i0 = (reg >> 2) * 8, j0 = (reg & 3) * 16;
  const int c0 = cc * 64, qb = cc * 8;            // chunks qb..qb+7

  // Phase 1: fp32 region -> LDS[cell][ch], coalesced 64B row loads
  #pragma unroll
  for (int it = 0; it < 8; ++it){
    int q = t + 256*it;                           // 0..2047
    int ch = q >> 5, rc = q & 31, ri = rc >> 2, c4 = rc & 3;
    const float4 v = *(const float4*)(f2 + ((size_t)(b*NC) + c0 + ch)*4096
                                        + (i0+ri)*64 + j0 + c4*4);
    float* dstL = lds + (ri*16 + c4*4)*65 + ch;   // cell stride 65 (pad)
    dstL[0] = v.x; dstL[65] = v.y; dstL[130] = v.z; dstL[195] = v.w;
  }
  __syncthreads();
  unsigned short* f2cB = f2c + (size_t)b*FB;

  // Level 0: 8 chunks x 128 cells, 16B stores
  #pragma unroll
  for (int it = 0; it < 4; ++it){
    int idx = t + 256*it;                         // 0..1023
    int cell = idx & 127, qi = idx >> 7;
    int ci = cell >> 4, cj = cell & 15;
    const float* src = lds + cell*65 + qi*8;
    uint4 v;
    v.x = pack2(src[0], src[1]); v.y = pack2(src[2], src[3]);
    v.z = pack2(src[4], src[5]); v.w = pack2(src[6], src[7]);
    int cellg = (i0+ci)*64 + j0+cj;
    *(uint4*)(f2cB + ((size_t)(qb+qi)*4096 + cellg)*8) = v;
  }
  // Level 1: 32 cells x 8 chunks; stash fp32 sums for level 2
  {
    int cell = t & 31, qi = t >> 5;
    int a = cell >> 3, bc = cell & 7;
    const float* p00 = lds + ((2*a)*16 + 2*bc)*65 + qi*8;
    float s[8];
    #pragma unroll
    for (int j = 0; j < 8; ++j){
      s[j] = p00[j] + p00[65+j] + p00[16*65+j] + p00[17*65+j];
      l1s[cell*65 + qi*8 + j] = s[j];
    }
    uint4 v;
    v.x = pack2(s[0]*0.25f, s[1]*0.25f); v.y = pack2(s[2]*0.25f, s[3]*0.25f);
    v.z = pack2(s[4]*0.25f, s[5]*0.25f); v.w = pack2(s[6]*0.25f, s[7]*0.25f);
    int cellg = ((i0>>1)+a)*32 + (j0>>1)+bc;
    *(uint4*)(f2cB + LVO1 + ((size_t)(qb+qi)*1024 + cellg)*8) = v;
  }
  __syncthreads();
  // Level 2: 8 cells x 8 chunks from l1 sums; stash for level 3
  if (t < 64){
    int cell = t & 7, qi = t >> 3;
    int a2 = cell >> 2, bc2 = cell & 3;
    float s[8];
    #pragma unroll
    for (int j = 0; j < 8; ++j){
      int ch = qi*8 + j;
      s[j] = l1s[((2*a2)*8   + 2*bc2  )*65 + ch] + l1s[((2*a2)*8   + 2*bc2+1)*65 + ch]
           + l1s[((2*a2+1)*8 + 2*bc2  )*65 + ch] + l1s[((2*a2+1)*8 + 2*bc2+1)*65 + ch];
      l2s[cell*65 + ch] = s[j];
    }
    uint4 v;
    v.x = pack2(s[0]*0.0625f, s[1]*0.0625f); v.y = pack2(s[2]*0.0625f, s[3]*0.0625f);
    v.z = pack2(s[4]*0.0625f, s[5]*0.0625f); v.w = pack2(s[6]*0.0625f, s[7]*0.0625f);
    int cellg = ((i0>>2)+a2)*16 + (j0>>2)+bc2;
    *(uint4*)(f2cB + LVO2 + ((size_t)(qb+qi)*256 + cellg)*8) = v;
  }
  __syncthreads();
  // Level 3: 2 cells x 8 chunks from l2 sums
  if (t < 16){
    int cl = t & 1, qi = t >> 1;
    float s[8];
    #pragma unroll
    for (int j = 0; j < 8; ++j){
      int ch = qi*8 + j;
      s[j] = l2s[(0*4 + 2*cl)*65 + ch] + l2s[(0*4 + 2*cl+1)*65 + ch]
           + l2s[(1*4 + 2*cl)*65 + ch] + l2s[(1*4 + 2*cl+1)*65 + ch];
    }
    const float m = 1.0f/64.0f;
    uint4 v;
    v.x = pack2(s[0]*m, s[1]*m); v.y = pack2(s[2]*m, s[3]*m);
    v.z = pack2(s[4]*m, s[5]*m); v.w = pack2(s[6]*m, s[7]*m);
    int cellg = (i0>>3)*8 + (j0>>3) + cl;
    *(uint4*)(f2cB + LVO3 + ((size_t)(qb+qi)*64 + cellg)*8) = v;
  }
}

// Block = 4x4 pixel tile, all 4 levels. Chunked A-layout (256B contiguous per
// quarter-wave). f1 fragments staged fp32->bf16 through LDS in the prologue
// (stride 264 shorts: fragment ds_read_b128 lands 2-way = conflict-free).
__global__ __launch_bounds__(256, 4) void lookup_main(const float* __restrict__ flow,
                 const float* __restrict__ f1,
                 const unsigned short* __restrict__ f2c,
                 float* __restrict__ out){
  const int lane = threadIdx.x & 63;
  const int wid  = threadIdx.x >> 6;
  const int blk = blockIdx.x;
  const int xs = blk & 7;                         // XCD swizzle: batch per XCD-pair
  const int bb = xs >> 1;
  const int tile = ((blk >> 3) << 1) | (xs & 1);  // 0..255
  const int ti4 = (tile >> 4) << 2;
  const int tj4 = (tile & 15) << 2;

  __shared__ float box[4*16*113];                 // [level][pixel][10x10, pad 113]
  __shared__ unsigned short f1s[16*264];          // [pixel][ch], pad stride 264
  __shared__ int   ls_y0[64], ls_x0[64];          // [level][pixel]
  __shared__ float ls_f[32];                      // fy[16], fx[16]
  __shared__ int   ls_meta[32];                   // [level][8]

  {
    float4* b4 = (float4*)box;
    for (int q = threadIdx.x; q < (4*16*113)/4; q += 256)
      b4[q] = make_float4(0.f, 0.f, 0.f, 0.f);
  }

  // Stage f1 columns for the tile's 16 pixels: thread t = channel t.
  {
    const float* f1b = f1 + ((size_t)(bb*NC) + threadIdx.x)*4096;
    #pragma unroll
    for (int r = 0; r < 4; ++r){
      const float4 v = *(const float4*)(f1b + (ti4 + r)*64 + tj4);
      const int px = r*4;
      f1s[(px+0)*264 + threadIdx.x] = f2b(v.x);
      f1s[(px+1)*264 + threadIdx.x] = f2b(v.y);
      f1s[(px+2)*264 + threadIdx.x] = f2b(v.z);
      f1s[(px+3)*264 + threadIdx.x] = f2b(v.w);
    }
  }

  const int n = lane & 15;                        // MFMA n = pixel column
  const int g = lane >> 4;                        // MFMA k-chunk group
  const int pn = ((ti4 + (n >> 2)) << 6) + tj4 + (n & 3);

  if (wid == 0){                                  // lane = k*16 + n
    const int k = g;
    const int i_n = pn >> 6, j_n = pn & 63;
    const float fy = flow[((bb*2 + 0)*64 + i_n)*64 + j_n];
    const float fx = flow[((bb*2 + 1)*64 + i_n)*64 + j_n];
    if (k == 0){ ls_f[n] = fy; ls_f[16 + n] = fx; }
    const int h = 64 >> k;
    const float inv = 1.0f / (float)(1 << k);
    const float s = (float)(h - 1) / (float)h;
    const float yc = ((float)i_n + fy) * inv;
    const float xc = ((float)j_n + fx) * inv;
    const int y0 = (int)floorf((yc - 4.0f) * s);
    const int x0 = (int)floorf((xc - 4.0f) * s);
    ls_y0[k*16 + n] = y0;
    ls_x0[k*16 + n] = x0;
    int ymin = y0, ymax = y0, xmin = x0, xmax = x0;
    #pragma unroll
    for (int m = 1; m < 16; m <<= 1){
      ymin = min(ymin, __shfl_xor(ymin, m));
      ymax = max(ymax, __shfl_xor(ymax, m));
      xmin = min(xmin, __shfl_xor(xmin, m));
      xmax = max(xmax, __shfl_xor(xmax, m));
    }
    if (n == 0){
      int ylo = max(ymin, 0), yhi = min(ymax + 9, h - 1);
      int xlo = max(xmin, 0), xhi = min(xmax + 9, h - 1);
      int H = max(yhi - ylo + 1, 0), W = max(xhi - xlo + 1, 0);
      int cells = W * H;
      ls_meta[k*8 + 0] = ylo;
      ls_meta[k*8 + 1] = xlo;
      ls_meta[k*8 + 2] = W;
      ls_meta[k*8 + 3] = cells;
      ls_meta[k*8 + 4] = __float_as_int(1.0f / (float)W);
      ls_meta[k*8 + 5] = (k==0) ? 0 : (k==1) ? LVO1 : (k==2) ? LVO2 : LVO3;
      ls_meta[k*8 + 6] = (cells + 15) >> 4;       // passes
    }
  }
  __syncthreads();

  // B fragments: f1 columns of the tile's 16 pixels, from LDS (registers)
  bf16x8 bfr[8];
  #pragma unroll
  for (int st = 0; st < 8; ++st)
    bfr[st] = *(const bf16x8*)(&f1s[n*264 + st*32 + g*8]);

  const int y0n0 = ls_y0[n],      x0n0 = ls_x0[n];
  const int y0n1 = ls_y0[16 + n], x0n1 = ls_x0[16 + n];
  const int y0n2 = ls_y0[32 + n], x0n2 = ls_x0[32 + n];
  const int y0n3 = ls_y0[48 + n], x0n3 = ls_x0[48 + n];
  const int pre1 = ls_meta[6];
  const int pre2 = pre1 + ls_meta[14];
  const int pre3 = pre2 + ls_meta[22];
  const int P    = pre3 + ls_meta[30];
  const unsigned short* f2cB = f2c + (size_t)bb*FB;

  for (int p = wid; p < P; p += 4){
    const int k  = (p >= pre1) + (p >= pre2) + (p >= pre3);
    const int lp = p - ((k==0) ? 0 : (k==1) ? pre1 : (k==2) ? pre2 : pre3);
    const int mb = k*8;
    const int ylo = ls_meta[mb], xlo = ls_meta[mb+1], W = ls_meta[mb+2];
    const int cells = ls_meta[mb+3];
    const float rW = __int_as_float(ls_meta[mb+4]);
    const int lvoc = ls_meta[mb+5];
    const int h = 64 >> k;
    const int ncl = h*h;
    const int base = lp << 4;

    const int idxA = min(base + n, cells - 1);
    const int by = (int)fmaf((float)idxA, rW, 0.004f);
    const int bx = idxA - by*W;
    const int cellIdx = (ylo + by)*h + (xlo + bx);
    const unsigned short* colp = f2cB + lvoc + ((size_t)(g*ncl + cellIdx) << 3);
    const int strideS = ncl << 5;   // shorts per st step (= 4 chunks)

    f32x4 acc0 = {0.f,0.f,0.f,0.f}, acc1 = {0.f,0.f,0.f,0.f};
    #pragma unroll
    for (int st = 0; st < 8; st += 2){
      bf16x8 a0 = *(const bf16x8*)(colp + (size_t)st*strideS);
      bf16x8 a1 = *(const bf16x8*)(colp + (size_t)(st+1)*strideS);
      acc0 = __builtin_amdgcn_mfma_f32_16x16x32_bf16(a0, bfr[st],   acc0, 0, 0, 0);
      acc1 = __builtin_amdgcn_mfma_f32_16x16x32_bf16(a1, bfr[st+1], acc1, 0, 0, 0);
    }
    // C/D: col = lane&15 = pixel n, row = cell = g*4 + r  [m89-verified]
    const int yb = (k==0) ? y0n0 : (k==1) ? y0n1 : (k==2) ? y0n2 : y0n3;
    const int xb = (k==0) ? x0n0 : (k==1) ? x0n1 : (k==2) ? x0n2 : x0n3;
    #pragma unroll
    for (int r = 0; r < 4; ++r){
      const int ci = base + (g << 2) + r;
      if (ci < cells){
        const int byc = (int)fmaf((float)ci, rW, 0.004f);
        const int bxc = ci - byc*W;
        const int ry = ylo + byc - yb;
        const int rx = xlo + bxc - xb;
        if ((unsigned)ry < 10u && (unsigned)rx < 10u)
          box[(k*16 + n)*113 + ry*10 + rx] = (acc0[r] + acc1[r]) * 0.0625f; // /sqrt(256)
      }
    }
  }
  __syncthreads();

  // Tap phase: wave w = level w; 16 pixels sequential, 41 taps in lanes.
  int dy = 0, dx = 0;
  {
    int rem = lane;
    #pragma unroll
    for (int ry = -4; ry <= 4; ++ry){
      int ab = ry < 0 ? -ry : ry;
      int ln = 9 - 2*ab;
      if (rem >= 0 && rem < ln){ dy = ry; dx = rem + (ab - 4); }
      rem -= ln;
    }
  }
  const int k = wid;
  const float inv = 1.0f / (float)(1 << k);
  const float s = (float)((64 >> k) - 1) / (float)(64 >> k);
  if (lane < 41){
    for (int t = 0; t < 16; ++t){
      const int pt = ((ti4 + (t >> 2)) << 6) + tj4 + (t & 3);
      const float fy = ls_f[t], fx = ls_f[16 + t];
      const float yc = ((float)(pt >> 6) + fy) * inv;
      const float xc = ((float)(pt & 63) + fx) * inv;
      const float py = (yc + (float)dy) * s;
      const float px = (xc + (float)dx) * s;
      const float fy0 = floorf(py), fx0 = floorf(px);
      const float wy1 = py - fy0, wx1 = px - fx0;
      const float wy0 = 1.0f - wy1, wx0 = 1.0f - wx1;
      const int iy = (int)fy0 - ls_y0[k*16 + t];
      const int ix = (int)fx0 - ls_x0[k*16 + t];
      const float* bx_ = &box[(k*16 + t)*113 + iy*10 + ix];
      const float v = wy0*(wx0*bx_[0] + wx1*bx_[1]) + wy1*(wx0*bx_[10] + wx1*bx_[11]);
      out[((size_t)(bb*4096 + pt)*4 + k)*41 + lane] = v;
    }
  }
}

extern "C" void kernel_launch(void* const* d_in, const int* in_sizes, int n_in,
                              void* d_out, int out_size, void* d_ws, size_t ws_size,
                              hipStream_t stream){
  const float* feat1 = (const float*)d_in[0];
  const float* feat2 = (const float*)d_in[1];
  const float* flow  = (const float*)d_in[2];
  float* out = (float*)d_out;
  unsigned short* f2c = (unsigned short*)d_ws;                 // 4*FB bf16 (chunked)

  prep_all<<<512, 256, 0, stream>>>(feat2, f2c);
  lookup_main<<<1024, 256, 0, stream>>>(flow, feat1, f2c, out);
}